// Round 3
// baseline (114.394 us; speedup 1.0000x reference)
//
#include <hip/hip_runtime.h>

// Problem: B=4, H=16, S=2048, D=64
//   scores = Q K^T / 8 ; attn = tanh(0.3*scores) ; out = attn V   (mask unused)
// Round 3: 4 waves x 64 q-rows (halves per-CU LDS K/V fragment re-reads,
//          the measured bottleneck). QT=256, 256 threads, 2 blocks/CU.

constexpr int S_LEN = 2048;
constexpr int DIM   = 64;
constexpr int QT    = 256;
constexpr int KT    = 64;

// tanh(a*x) = 1 - 2/(exp2(2*a*x*log2e)+1); a = 0.3/8 = 0.0375
constexpr float C_EXP2 = 0.10820212528f;

typedef __bf16 bf16_t;
typedef bf16_t bf16x4 __attribute__((ext_vector_type(4)));
typedef bf16_t bf16x8 __attribute__((ext_vector_type(8)));
typedef float  f32x4  __attribute__((ext_vector_type(4)));

__device__ inline bf16x8 to_bf8(float4 a, float4 b) {
    bf16x8 v;
    v[0] = (bf16_t)a.x; v[1] = (bf16_t)a.y; v[2] = (bf16_t)a.z; v[3] = (bf16_t)a.w;
    v[4] = (bf16_t)b.x; v[5] = (bf16_t)b.y; v[6] = (bf16_t)b.z; v[7] = (bf16_t)b.w;
    return v;
}

__global__ __launch_bounds__(256, 2) void tanh_attn_kernel(
    const float* __restrict__ Q, const float* __restrict__ K,
    const float* __restrict__ V, float* __restrict__ O)
{
    const int tid  = threadIdx.x;
    const int lane = tid & 63;
    const int wv   = tid >> 6;          // wave id 0..3 (64 q-rows each)
    const int lr   = lane & 15;
    const int lg   = lane >> 4;

    // XCD-aware bijective swizzle (grid=512, 512%8==0)
    const int nwg = gridDim.x;
    const int bid = (blockIdx.x & 7) * (nwg >> 3) + (blockIdx.x >> 3);
    const int qtile = bid & 7;          // S/QT = 8
    const int bh    = bid >> 3;         // 0..63
    const int base  = bh * (S_LEN * DIM);
    const int q0    = qtile * QT;

    __shared__ bf16_t Ql[QT * DIM];     // 32 KB (doubles as per-wave P buffer)
    __shared__ bf16_t Kl[KT * DIM];     // 8 KB, [kv][d] swizzled
    __shared__ bf16_t Vt[DIM * KT];     // 8 KB, [d][kv] swizzled (V transposed)

    // ---- stage Q tile (f32 -> bf16, XOR swizzle (row&7)<<3 on 8-elem chunks) ----
    #pragma unroll
    for (int it = 0; it < 8; ++it) {
        int cid = tid + it * 256;           // 0..2047
        int r   = cid >> 3;
        int c8  = (cid & 7) * 8;
        const float* src = Q + base + (q0 + r) * DIM + c8;
        float4 a = *(const float4*)src;
        float4 b = *(const float4*)(src + 4);
        *(bf16x8*)&Ql[r * DIM + (c8 ^ ((r & 7) << 3))] = to_bf8(a, b);
    }
    __syncthreads();

    // ---- hoist Q B-fragments: wave covers q rows wv*64 .. wv*64+63 ----
    bf16x8 qa[4][2];
    #pragma unroll
    for (int rt = 0; rt < 4; ++rt)
        #pragma unroll
        for (int ks = 0; ks < 2; ++ks) {
            int r = wv * 64 + rt * 16 + lr;
            int c = ks * 32 + lg * 8;
            qa[rt][ks] = *(const bf16x8*)&Ql[r * DIM + (c ^ ((r & 7) << 3))];
        }

    f32x4 oacc[4][4] = {};

    bf16_t* Pl = Ql + wv * (64 * KT);   // per-wave P slice [64][64] swizzled

    for (int kt = 0; kt < S_LEN / KT; ++kt) {
        const int k0 = kt * KT;
        __syncthreads();   // protect Kl/Vt (and Pl vs qa on first iter)

        // ---- stage K tile [kv][d]: 512 chunks, 2 per thread ----
        #pragma unroll
        for (int it = 0; it < 2; ++it) {
            int cid = tid + it * 256;
            int r   = cid >> 3;             // 0..63
            int c8  = (cid & 7) * 8;
            const float* src = K + base + (k0 + r) * DIM + c8;
            float4 a = *(const float4*)src;
            float4 b = *(const float4*)(src + 4);
            *(bf16x8*)&Kl[r * DIM + (c8 ^ ((r & 7) << 3))] = to_bf8(a, b);
        }
        // ---- stage V transposed: Vt[d][kv] ----
        #pragma unroll
        for (int it = 0; it < 2; ++it) {
            int cid = tid + it * 256;
            int d   = cid & 63;
            int kv0 = ((cid >> 6) & 7) * 8;
            const float* src = V + base + (k0 + kv0) * DIM + d;
            bf16x8 v;
            #pragma unroll
            for (int j = 0; j < 8; ++j) v[j] = (bf16_t)src[j * DIM];
            *(bf16x8*)&Vt[d * KT + (kv0 ^ ((d & 7) << 3))] = v;
        }
        __syncthreads();

        // ---- GEMM1 (swapped): S^T = K · Q^T; D[m=kv][n=q] ----
        f32x4 sacc[4][4] = {};
        #pragma unroll
        for (int ct = 0; ct < 4; ++ct) {
            int r = ct * 16 + lr;           // kv
            bf16x8 kb0 = *(const bf16x8*)&Kl[r * DIM + ((lg * 8)      ^ ((r & 7) << 3))];
            bf16x8 kb1 = *(const bf16x8*)&Kl[r * DIM + ((32 + lg * 8) ^ ((r & 7) << 3))];
            #pragma unroll
            for (int rt = 0; rt < 4; ++rt) {
                sacc[rt][ct] = __builtin_amdgcn_mfma_f32_16x16x32_bf16(kb0, qa[rt][0], sacc[rt][ct], 0, 0, 0);
                sacc[rt][ct] = __builtin_amdgcn_mfma_f32_16x16x32_bf16(kb1, qa[rt][1], sacc[rt][ct], 0, 0, 0);
            }
        }

        // ---- tanh + packed P store: lane holds q=rt*16+lr, kv=ct*16+lg*4+j ----
        #pragma unroll
        for (int rt = 0; rt < 4; ++rt)
            #pragma unroll
            for (int ct = 0; ct < 4; ++ct) {
                bf16x4 p4;
                #pragma unroll
                for (int j = 0; j < 4; ++j) {
                    float t = __builtin_amdgcn_exp2f(sacc[rt][ct][j] * C_EXP2);
                    p4[j] = (bf16_t)(1.0f - 2.0f * __builtin_amdgcn_rcpf(t + 1.0f));
                }
                int q  = rt * 16 + lr;
                int c0 = ct * 16 + lg * 4;
                *(bf16x4*)&Pl[q * KT + (c0 ^ ((q & 7) << 3))] = p4;
            }

        // ---- load P A-fragments (same-wave LDS slice, no barrier) ----
        bf16x8 pa[4][2];
        #pragma unroll
        for (int rt = 0; rt < 4; ++rt)
            #pragma unroll
            for (int ks = 0; ks < 2; ++ks) {
                int r = rt * 16 + lr;
                pa[rt][ks] = *(const bf16x8*)&Pl[r * KT + ((ks * 32 + lg * 8) ^ ((r & 7) << 3))];
            }

        // ---- GEMM2: O += P · V ----
        #pragma unroll
        for (int dt = 0; dt < 4; ++dt) {
            int d = dt * 16 + lr;
            bf16x8 vb0 = *(const bf16x8*)&Vt[d * KT + ((lg * 8)      ^ ((d & 7) << 3))];
            bf16x8 vb1 = *(const bf16x8*)&Vt[d * KT + ((32 + lg * 8) ^ ((d & 7) << 3))];
            #pragma unroll
            for (int rt = 0; rt < 4; ++rt) {
                oacc[rt][dt] = __builtin_amdgcn_mfma_f32_16x16x32_bf16(pa[rt][0], vb0, oacc[rt][dt], 0, 0, 0);
                oacc[rt][dt] = __builtin_amdgcn_mfma_f32_16x16x32_bf16(pa[rt][1], vb1, oacc[rt][dt], 0, 0, 0);
            }
        }
    }

    // ---- epilogue: write O (f32) ----
    #pragma unroll
    for (int rt = 0; rt < 4; ++rt)
        #pragma unroll
        for (int dt = 0; dt < 4; ++dt)
            #pragma unroll
            for (int j = 0; j < 4; ++j) {
                int q = q0 + wv * 64 + rt * 16 + lg * 4 + j;
                int d = dt * 16 + lr;
                O[base + q * DIM + d] = oacc[rt][dt][j];
            }
}

extern "C" void kernel_launch(void* const* d_in, const int* in_sizes, int n_in,
                              void* d_out, int out_size, void* d_ws, size_t ws_size,
                              hipStream_t stream) {
    const float* Q = (const float*)d_in[0];
    const float* K = (const float*)d_in[1];
    const float* V = (const float*)d_in[2];
    float* O = (float*)d_out;
    dim3 grid(64 * (S_LEN / QT));   // 512 blocks
    dim3 block(256);
    hipLaunchKernelGGL(tanh_attn_kernel, grid, block, 0, stream, Q, K, V, O);
}

// Round 4
// 104.773 us; speedup vs baseline: 1.0918x; 1.0918x over previous
//
#include <hip/hip_runtime.h>

// Problem: B=4, H=16, S=2048, D=64
//   scores = Q K^T / 8 ; attn = tanh(0.3*scores) ; out = attn V   (mask unused)
// Round 4: R2 structure (8 waves x 32 q-rows) + 2-phase pipeline:
//   double-buffered K/V LDS, ONE barrier per K-tile, reg-prefetch of the
//   next tile issued right after the barrier (hidden under compute),
//   ds_write after compute, setprio(1) around MFMA clusters.

constexpr int S_LEN = 2048;
constexpr int DIM   = 64;
constexpr int QT    = 256;
constexpr int KT    = 64;
constexpr int NKT   = S_LEN / KT;   // 32

// tanh(a*x) = 1 - 2/(exp2(2*a*x*log2e)+1); a = 0.3/8 = 0.0375
constexpr float C_EXP2 = 0.10820212528f;

typedef __bf16 bf16_t;
typedef bf16_t bf16x4 __attribute__((ext_vector_type(4)));
typedef bf16_t bf16x8 __attribute__((ext_vector_type(8)));
typedef float  f32x4  __attribute__((ext_vector_type(4)));

__device__ inline bf16x8 to_bf8(float4 a, float4 b) {
    bf16x8 v;
    v[0] = (bf16_t)a.x; v[1] = (bf16_t)a.y; v[2] = (bf16_t)a.z; v[3] = (bf16_t)a.w;
    v[4] = (bf16_t)b.x; v[5] = (bf16_t)b.y; v[6] = (bf16_t)b.z; v[7] = (bf16_t)b.w;
    return v;
}

__global__ __launch_bounds__(512, 4) void tanh_attn_kernel(
    const float* __restrict__ Q, const float* __restrict__ K,
    const float* __restrict__ V, float* __restrict__ O)
{
    const int tid  = threadIdx.x;
    const int lane = tid & 63;
    const int wv   = tid >> 6;          // wave id 0..7 (32 q-rows each)
    const int lr   = lane & 15;
    const int lg   = lane >> 4;

    // XCD-aware bijective swizzle (grid=512, 512%8==0)
    const int nwg = gridDim.x;
    const int bid = (blockIdx.x & 7) * (nwg >> 3) + (blockIdx.x >> 3);
    const int qtile = bid & 7;          // S/QT = 8
    const int bh    = bid >> 3;         // 0..63
    const int base  = bh * (S_LEN * DIM);
    const int q0    = qtile * QT;

    __shared__ bf16_t Ql[QT * DIM];     // 32 KB (Q frags; reused as per-wave P)
    __shared__ bf16_t Kl[2][KT * DIM];  // 2 x 8 KB, [kv][d] swizzled
    __shared__ bf16_t Vt[2][DIM * KT];  // 2 x 8 KB, [d][kv] swizzled (V^T)

    const float* Kb = K + base;
    const float* Vb = V + base;

    // fixed per-thread staging map
    const int sr  = tid >> 3;           // K row 0..63
    const int sc8 = (tid & 7) * 8;      // K col chunk
    const int sd  = tid & 63;           // V d column
    const int skv = (tid >> 6) * 8;     // V kv chunk base

    // ---- issue tile-0 prefetch first (latency overlaps Q staging) ----
    float4 ka, kb2;
    float  vv[8];
    {
        const float* src = Kb + sr * DIM + sc8;
        ka  = *(const float4*)src;
        kb2 = *(const float4*)(src + 4);
        const float* vsrc = Vb + skv * DIM + sd;
        #pragma unroll
        for (int j = 0; j < 8; ++j) vv[j] = vsrc[j * DIM];
    }

    // ---- stage Q tile (f32 -> bf16, XOR swizzle (row&7)<<3) ----
    #pragma unroll
    for (int it = 0; it < 4; ++it) {
        int cid = tid + it * 512;           // 0..2047
        int r   = cid >> 3;
        int c8  = (cid & 7) * 8;
        const float* src = Q + base + (q0 + r) * DIM + c8;
        float4 a = *(const float4*)src;
        float4 b = *(const float4*)(src + 4);
        *(bf16x8*)&Ql[r * DIM + (c8 ^ ((r & 7) << 3))] = to_bf8(a, b);
    }
    __syncthreads();

    // ---- hoist Q fragments (wave's own 32 rows; its P slice = same region,
    //      so no further barrier needed) ----
    bf16x8 qa[2][2];
    #pragma unroll
    for (int rt = 0; rt < 2; ++rt)
        #pragma unroll
        for (int ks = 0; ks < 2; ++ks) {
            int r = wv * 32 + rt * 16 + lr;
            int c = ks * 32 + lg * 8;
            qa[rt][ks] = *(const bf16x8*)&Ql[r * DIM + (c ^ ((r & 7) << 3))];
        }

    // ---- write tile 0 into buffer 0 ----
    {
        *(bf16x8*)&Kl[0][sr * DIM + (sc8 ^ ((sr & 7) << 3))] = to_bf8(ka, kb2);
        bf16x8 v;
        #pragma unroll
        for (int j = 0; j < 8; ++j) v[j] = (bf16_t)vv[j];
        *(bf16x8*)&Vt[0][sd * KT + (skv ^ ((sd & 7) << 3))] = v;
    }

    f32x4 oacc[2][4] = {};
    bf16_t* Pl = Ql + wv * (32 * KT);   // per-wave P slice [32][64] swizzled

    #pragma unroll 2
    for (int kt = 0; kt < NKT; ++kt) {
        const int cur = kt & 1;

        // ONE barrier per tile: publishes buf[cur] writes (end of kt-1) and
        // proves all waves finished reading buf[cur^1] (compute of kt-1).
        __syncthreads();

        // issue next-tile global loads AFTER the barrier (so the barrier's
        // vmcnt(0) drain never waits on them); land during compute below.
        if (kt + 1 < NKT) {
            const int k0n = (kt + 1) * KT;
            const float* src = Kb + (k0n + sr) * DIM + sc8;
            ka  = *(const float4*)src;
            kb2 = *(const float4*)(src + 4);
            const float* vsrc = Vb + (k0n + skv) * DIM + sd;
            #pragma unroll
            for (int j = 0; j < 8; ++j) vv[j] = vsrc[j * DIM];
        }

        const bf16_t* Kc = Kl[cur];
        const bf16_t* Vc = Vt[cur];

        // ---- GEMM1 (swapped): S^T = K · Q^T; D[m=kv][n=q] ----
        f32x4 sacc[2][4] = {};
        __builtin_amdgcn_s_setprio(1);
        #pragma unroll
        for (int ct = 0; ct < 4; ++ct) {
            int r = ct * 16 + lr;           // kv
            bf16x8 kf0 = *(const bf16x8*)&Kc[r * DIM + ((lg * 8)      ^ ((r & 7) << 3))];
            bf16x8 kf1 = *(const bf16x8*)&Kc[r * DIM + ((32 + lg * 8) ^ ((r & 7) << 3))];
            #pragma unroll
            for (int rt = 0; rt < 2; ++rt) {
                sacc[rt][ct] = __builtin_amdgcn_mfma_f32_16x16x32_bf16(kf0, qa[rt][0], sacc[rt][ct], 0, 0, 0);
                sacc[rt][ct] = __builtin_amdgcn_mfma_f32_16x16x32_bf16(kf1, qa[rt][1], sacc[rt][ct], 0, 0, 0);
            }
        }
        __builtin_amdgcn_s_setprio(0);

        // ---- tanh + packed P store: lane holds q=rt*16+lr, kv=ct*16+lg*4+j ----
        #pragma unroll
        for (int rt = 0; rt < 2; ++rt)
            #pragma unroll
            for (int ct = 0; ct < 4; ++ct) {
                bf16x4 p4;
                #pragma unroll
                for (int j = 0; j < 4; ++j) {
                    float t = __builtin_amdgcn_exp2f(sacc[rt][ct][j] * C_EXP2);
                    p4[j] = (bf16_t)(1.0f - 2.0f * __builtin_amdgcn_rcpf(t + 1.0f));
                }
                int q  = rt * 16 + lr;
                int c0 = ct * 16 + lg * 4;
                *(bf16x4*)&Pl[q * KT + (c0 ^ ((q & 7) << 3))] = p4;
            }

        // ---- P A-fragments (same-wave LDS slice, no barrier) ----
        bf16x8 pa[2][2];
        #pragma unroll
        for (int rt = 0; rt < 2; ++rt)
            #pragma unroll
            for (int ks = 0; ks < 2; ++ks) {
                int r = rt * 16 + lr;
                pa[rt][ks] = *(const bf16x8*)&Pl[r * KT + ((ks * 32 + lg * 8) ^ ((r & 7) << 3))];
            }

        // ---- GEMM2: O += P · V ----
        __builtin_amdgcn_s_setprio(1);
        #pragma unroll
        for (int dt = 0; dt < 4; ++dt) {
            int d = dt * 16 + lr;
            bf16x8 vf0 = *(const bf16x8*)&Vc[d * KT + ((lg * 8)      ^ ((d & 7) << 3))];
            bf16x8 vf1 = *(const bf16x8*)&Vc[d * KT + ((32 + lg * 8) ^ ((d & 7) << 3))];
            #pragma unroll
            for (int rt = 0; rt < 2; ++rt) {
                oacc[rt][dt] = __builtin_amdgcn_mfma_f32_16x16x32_bf16(pa[rt][0], vf0, oacc[rt][dt], 0, 0, 0);
                oacc[rt][dt] = __builtin_amdgcn_mfma_f32_16x16x32_bf16(pa[rt][1], vf1, oacc[rt][dt], 0, 0, 0);
            }
        }
        __builtin_amdgcn_s_setprio(0);

        // ---- write next tile into the other buffer (overlaps: loads landed
        //      during compute; other waves may still be computing — they only
        //      read buf[cur], and the next barrier publishes these writes) ----
        if (kt + 1 < NKT) {
            const int nxt = cur ^ 1;
            *(bf16x8*)&Kl[nxt][sr * DIM + (sc8 ^ ((sr & 7) << 3))] = to_bf8(ka, kb2);
            bf16x8 v;
            #pragma unroll
            for (int j = 0; j < 8; ++j) v[j] = (bf16_t)vv[j];
            *(bf16x8*)&Vt[nxt][sd * KT + (skv ^ ((sd & 7) << 3))] = v;
        }
    }

    // ---- epilogue: write O (f32) ----
    #pragma unroll
    for (int rt = 0; rt < 2; ++rt)
        #pragma unroll
        for (int dt = 0; dt < 4; ++dt)
            #pragma unroll
            for (int j = 0; j < 4; ++j) {
                int q = q0 + wv * 32 + rt * 16 + lg * 4 + j;
                int d = dt * 16 + lr;
                O[base + q * DIM + d] = oacc[rt][dt][j];
            }
}

extern "C" void kernel_launch(void* const* d_in, const int* in_sizes, int n_in,
                              void* d_out, int out_size, void* d_ws, size_t ws_size,
                              hipStream_t stream) {
    const float* Q = (const float*)d_in[0];
    const float* K = (const float*)d_in[1];
    const float* V = (const float*)d_in[2];
    float* O = (float*)d_out;
    dim3 grid(64 * (S_LEN / QT));   // 512 blocks
    dim3 block(512);
    hipLaunchKernelGGL(tanh_attn_kernel, grid, block, 0, stream, Q, K, V, O);
}